// Round 8
// baseline (1964.533 us; speedup 1.0000x reference)
//
#include <hip/hip_runtime.h>
#include <hip/hip_bf16.h>
#include <math.h>

#define BATCH   1024
#define SEQ     80
#define EMB     512
#define UNITS   512
#define NBG     16           // batch groups of 64 rows
#define NJ      8            // col groups of 64 cols
#define THREADS 512          // 8 waves; wave w: row-grp w>>1, col-pair w&1

#define H0_OFF (2u * 1024 * 1024)
#define H1_OFF (4u * 1024 * 1024)
#define FL_OFF (6u * 1024 * 1024)

typedef __attribute__((ext_vector_type(8))) short              bf16x8;
typedef __attribute__((ext_vector_type(8))) unsigned short     u16x8;
typedef __attribute__((ext_vector_type(4))) float              f32x4;
typedef __attribute__((ext_vector_type(2))) unsigned long long u64x2;

__device__ inline unsigned short f2bf(float f) {
    __hip_bfloat16 h = __float2bfloat16(f);
    return *reinterpret_cast<unsigned short*>(&h);
}
__device__ inline float bf2f(unsigned short u) {
    unsigned int x = ((unsigned int)u) << 16;
    return __uint_as_float(x);
}
__device__ inline float tanh_fast(float x) {
    float e = __expf(2.f * x);
    return 1.f - 2.f / (e + 1.f);
}
__device__ inline u16x8 pack8(float4 p0, float4 p1) {
    u16x8 v;
    v[0]=f2bf(p0.x); v[1]=f2bf(p0.y); v[2]=f2bf(p0.z); v[3]=f2bf(p0.w);
    v[4]=f2bf(p1.x); v[5]=f2bf(p1.y); v[6]=f2bf(p1.z); v[7]=f2bf(p1.w);
    return v;
}
__device__ inline void st_u16(unsigned short* p, unsigned short v) {
    __hip_atomic_store(p, v, __ATOMIC_RELAXED, __HIP_MEMORY_SCOPE_AGENT);
}
__device__ inline unsigned long long ld_u64(const unsigned long long* p) {
    return __hip_atomic_load(p, __ATOMIC_RELAXED, __HIP_MEMORY_SCOPE_AGENT);
}
__device__ inline int ld_flag(const int* p) {
    return __hip_atomic_load(p, __ATOMIC_RELAXED, __HIP_MEMORY_SCOPE_AGENT);
}

// ---------------------------------------------------------------------------
// Pack weights, frag-order, per (type, j) 128KB block image (same as r7):
// g = ((type*8 + j)*2 + mat)*64 + kk*4 + nt
// type0: mat0=W0x mat1=W0h ; type1: mat0=W1x mat1=W1h
// elem(lane,jj) = M[kk*32 + (lane>>4)*8 + jj][j*64 + nt*16 + (lane&15)]
// ---------------------------------------------------------------------------
__global__ __launch_bounds__(256) void pack_weights(
    const float* __restrict__ W0x, const float* __restrict__ W0h,
    const float* __restrict__ W1x, const float* __restrict__ W1h,
    unsigned short* __restrict__ wpack)
{
    int g    = blockIdx.x * 4 + (threadIdx.x >> 6);   // 0..2047
    int lane = threadIdx.x & 63;
    int type = g >> 10;
    int j    = (g >> 7) & 7;
    int mat  = (g >> 6) & 1;
    int kk   = (g >> 2) & 15;
    int nt   = g & 3;
    const float* M = type ? (mat ? W1h : W1x) : (mat ? W0h : W0x);
    int col  = j * 64 + nt * 16 + (lane & 15);
    int rowb = kk * 32 + (lane >> 4) * 8;

    u16x8 v;
#pragma unroll
    for (int jj = 0; jj < 8; ++jj)
        v[jj] = f2bf(M[(size_t)(rowb + jj) * UNITS + col]);
    *(u16x8*)(wpack + (size_t)g * 512 + lane * 8) = v;
}

// LDS layout (ushort offsets)
#define WLD(mat, kk, nt)  ((((mat)*16 + (kk))*4 + (nt)) * 512)

// A-frags straight from h-buffer to registers (no LDS, no barriers):
// lane needs h[rbase+arow][ks*32 + quad*8 ..+8] -> two relaxed u64 loads
#define GATHER_REG(AV, HB, PAR)                                                \
    do {                                                                       \
        const unsigned long long* hs_ = (const unsigned long long*)            \
            ((HB) + ((size_t)(PAR) * BATCH + rbase + arow) * UNITS);           \
        _Pragma("unroll")                                                      \
        for (int ks_ = 0; ks_ < 16; ++ks_) {                                   \
            u64x2 q_;                                                          \
            q_[0] = ld_u64(hs_ + ks_ * 8 + quad * 2);                          \
            q_[1] = ld_u64(hs_ + ks_ * 8 + quad * 2 + 1);                      \
            (AV)[ks_] = *(bf16x8*)&q_;                                         \
        }                                                                      \
    } while (0)

// acc += A(AV[16]) @ Wmat (B resident in LDS, ds_read_b128 per slab)
#define GEMM_LDS(AV, MAT, A0, A1)                                              \
    do {                                                                       \
        _Pragma("unroll")                                                      \
        for (int kg_ = 0; kg_ < 16; ++kg_) {                                   \
            bf16x8 b0_ = *(const bf16x8*)(wlds + WLD(MAT, kg_, nt0) + lane*8); \
            bf16x8 b1_ = *(const bf16x8*)(wlds + WLD(MAT, kg_, nt1) + lane*8); \
            A0 = __builtin_amdgcn_mfma_f32_16x16x32_bf16((AV)[kg_], b0_, A0,   \
                                                         0, 0, 0);             \
            A1 = __builtin_amdgcn_mfma_f32_16x16x32_bf16((AV)[kg_], b1_, A1,   \
                                                         0, 0, 0);             \
        }                                                                      \
    } while (0)

// x(TT) straight from emb to registers (f32->bf16), then @ W0x (mat 0)
#define XSTAGE_REG(TT, A0, A1)                                                 \
    do {                                                                       \
        int t_   = (TT) < SEQ ? (TT) : SEQ - 1;                                \
        int idx_ = inputs[(rbase + arow) * SEQ + t_];                          \
        const float4* ep_ = (const float4*)(emb + (size_t)idx_ * EMB);         \
        bf16x8 xa_[16];                                                        \
        _Pragma("unroll")                                                      \
        for (int ks_ = 0; ks_ < 16; ++ks_) {                                   \
            float4 pa_ = ep_[ks_ * 8 + quad * 2];                              \
            float4 pb_ = ep_[ks_ * 8 + quad * 2 + 1];                          \
            u16x8 vv_ = pack8(pa_, pb_);                                       \
            xa_[ks_] = *(bf16x8*)&vv_;                                         \
        }                                                                      \
        GEMM_LDS(xa_, 0, A0, A1);                                              \
    } while (0)

#define PUBLISH(HB, PAR, A0, A1)                                               \
    do {                                                                       \
        unsigned short* d_ = (HB) +                                            \
            ((size_t)(PAR) * BATCH + rbase + rg * 16 + quad * 4) * UNITS       \
            + c0 + l15;                                                        \
        _Pragma("unroll")                                                      \
        for (int i_ = 0; i_ < 4; ++i_) {                                       \
            st_u16(d_ + (size_t)i_ * UNITS + nt0 * 16, f2bf(tanh_fast(A0[i_]))); \
            st_u16(d_ + (size_t)i_ * UNITS + nt1 * 16, f2bf(tanh_fast(A1[i_]))); \
        }                                                                      \
    } while (0)

// ---------------------------------------------------------------------------
// 256 blocks = 2 types x 16 bg x 8 j, co-resident 1/CU. Weights in LDS
// (128KB, loaded once). A-side h gathers go DIRECT to registers (no ring,
// no barriers). L0: h0(r) = tanh(b0 + x_r@W0x + h0(r-1)@W0h), x-term in the
// post-release shadow. L1: h1(s) = tanh(b1 + h0(s)@W1x + h1(s-1)@W1h).
// Spins: L0 r: F0>=r, F1>=r-1.  L1 s: F0>=s+1, F1>=s.  (same as r7)
// Publish/spin/fence/barrier protocol identical to the validated baseline.
// ---------------------------------------------------------------------------
__global__ __launch_bounds__(THREADS, 2) void rnn_lsr(
    const int*   __restrict__ inputs,
    const float* __restrict__ emb,
    const float* __restrict__ b0,
    const float* __restrict__ b1,
    const unsigned short* __restrict__ wpack,
    unsigned short* __restrict__ h0buf,   // [2][1024][512] bf16 (par1 zeroed)
    unsigned short* __restrict__ h1buf,   // [2][1024][512] bf16 (par1 zeroed)
    int* __restrict__ flag0,              // [16][8]
    int* __restrict__ flag1,              // [16][8]
    const float* __restrict__ Wout,
    const float* __restrict__ bout,
    float*       __restrict__ out)
{
    __shared__ __align__(16) unsigned short wlds[2 * 16 * 4 * 512];  // 128KB

    const int tid   = threadIdx.x;
    const int w     = tid >> 6;
    const int lane  = tid & 63;
    const int quad  = lane >> 4;
    const int l15   = lane & 15;
    const int type  = blockIdx.x >> 7;    // 0 = L0, 1 = L1
    const int bidx  = blockIdx.x & 127;
    const int bg    = bidx >> 3;          // 0..15
    const int j     = bidx & 7;           // 0..7
    const int rbase = bg * 64;
    const int c0    = j * 64;

    const int rg   = w >> 1;              // row-group 0..3 (16 rows each)
    const int ntp  = w & 1;
    const int nt0  = 2 * ntp, nt1 = nt0 + 1;
    const int arow = rg * 16 + l15;       // this lane's A row

    // ---- stage this block's 128KB weight image into LDS (once) ----
    {
        const unsigned short* wsrc = wpack + (size_t)(type * 8 + j) * 128 * 512;
#pragma unroll
        for (int i = 0; i < 16; ++i)
            *(u16x8*)(wlds + (size_t)(i * 512 + tid) * 8) =
                *(const u16x8*)(wsrc + (size_t)(i * 512 + tid) * 8);
    }
    __syncthreads();

    const float* bp   = type ? b1 : b0;
    const float  bia0 = bp[c0 + nt0 * 16 + l15];
    const float  bia1 = bp[c0 + nt1 * 16 + l15];

    if (type == 0) {
        // =================== L0: h0 recurrence ===================
        f32x4 aX0 = {bia0, bia0, bia0, bia0};
        f32x4 aX1 = {bia1, bia1, bia1, bia1};
        XSTAGE_REG(0, aX0, aX1);                      // preX(0)

        for (int r = 0; r < SEQ; ++r) {
            const int par = r & 1;
            if (tid < 8)
                while (ld_flag(flag0 + bg * 8 + tid) < r)
                    __builtin_amdgcn_s_sleep(1);
            else if (tid < 16)
                while (ld_flag(flag1 + bg * 8 + (tid - 8)) < r - 1)
                    __builtin_amdgcn_s_sleep(1);
            __asm__ volatile("" ::: "memory");
            __syncthreads();

            f32x4 a0 = aX0, a1 = aX1;
            bf16x8 av[16];
            GATHER_REG(av, h0buf, par ^ 1);           // h0(r-1) -> regs
            GEMM_LDS(av, 1, a0, a1);                  // + h0(r-1) @ W0h
            PUBLISH(h0buf, par, a0, a1);              // h0(r)
            __syncthreads();                          // drain publishes
            if (tid == 0)
                __hip_atomic_store(flag0 + bg * 8 + j, r + 1,
                                   __ATOMIC_RELEASE, __HIP_MEMORY_SCOPE_AGENT);

            // shadow: preX(r+1) = b0 + x(r+1) @ W0x
            aX0 = (f32x4){bia0, bia0, bia0, bia0};
            aX1 = (f32x4){bia1, bia1, bia1, bia1};
            XSTAGE_REG(r + 1, aX0, aX1);
        }
    } else {
        // =================== L1: h1 recurrence + epilogue ===================
        for (int s = 0; s < SEQ; ++s) {
            const int par = s & 1;
            if (tid < 8)
                while (ld_flag(flag0 + bg * 8 + tid) < s + 1)
                    __builtin_amdgcn_s_sleep(1);
            else if (tid < 16)
                while (ld_flag(flag1 + bg * 8 + (tid - 8)) < s)
                    __builtin_amdgcn_s_sleep(1);
            __asm__ volatile("" ::: "memory");
            __syncthreads();

            f32x4 a0 = {bia0, bia0, bia0, bia0};
            f32x4 a1 = {bia1, bia1, bia1, bia1};
            bf16x8 av0[16], av1[16];
            GATHER_REG(av0, h0buf, par);              // h0(s)   -> regs
            GATHER_REG(av1, h1buf, par ^ 1);          // h1(s-1) -> regs
            GEMM_LDS(av0, 0, a0, a1);                 // + h0(s)   @ W1x
            GEMM_LDS(av1, 1, a0, a1);                 // + h1(s-1) @ W1h
            PUBLISH(h1buf, par, a0, a1);              // h1(s)
            __syncthreads();                          // drain publishes
            if (tid == 0)
                __hip_atomic_store(flag1 + bg * 8 + j, s + 1,
                                   __ATOMIC_RELEASE, __HIP_MEMORY_SCOPE_AGENT);
        }

        // epilogue: j==0 blocks reduce h1(79) (parity 1) -> out
        if (j == 0) {
            if (tid < 8)
                while (ld_flag(flag1 + bg * 8 + tid) < SEQ)
                    __builtin_amdgcn_s_sleep(1);
            __asm__ volatile("" ::: "memory");
            __syncthreads();
            const unsigned long long* hs = (const unsigned long long*)
                (h1buf + ((size_t)((SEQ - 1) & 1) * BATCH + rbase) * UNITS);
#pragma unroll
            for (int i = 0; i < 8; ++i) {
                int row = w * 8 + i;
                unsigned long long q0 = ld_u64(hs + row * 128 + lane * 2);
                unsigned long long q1 = ld_u64(hs + row * 128 + lane * 2 + 1);
                u64x2 qq; qq[0] = q0; qq[1] = q1;
                u16x8 hv = *(u16x8*)&qq;
                float sacc = 0.f;
#pragma unroll
                for (int k = 0; k < 8; ++k)
                    sacc += bf2f(hv[k]) * Wout[lane * 8 + k];
#pragma unroll
                for (int off = 32; off > 0; off >>= 1)
                    sacc += __shfl_down(sacc, off);
                if (lane == 0) {
                    float z = sacc + bout[0];
                    out[rbase + row] = 1.f / (1.f + __expf(-z));
                }
            }
        }
    }
}

extern "C" void kernel_launch(void* const* d_in, const int* in_sizes, int n_in,
                              void* d_out, int out_size, void* d_ws, size_t ws_size,
                              hipStream_t stream) {
    const int*   inputs = (const int*)d_in[0];
    const float* emb    = (const float*)d_in[1];
    const float* W0x    = (const float*)d_in[2];
    const float* W0h    = (const float*)d_in[3];
    const float* b0     = (const float*)d_in[4];
    const float* W1x    = (const float*)d_in[5];
    const float* W1h    = (const float*)d_in[6];
    const float* b1     = (const float*)d_in[7];
    const float* Wout   = (const float*)d_in[8];
    const float* bout   = (const float*)d_in[9];
    float*       out    = (float*)d_out;

    unsigned short* wpack = (unsigned short*)d_ws;                      // 2 MB
    unsigned short* h0buf = (unsigned short*)((char*)d_ws + H0_OFF);    // 2 MB
    unsigned short* h1buf = (unsigned short*)((char*)d_ws + H1_OFF);    // 2 MB
    int* flag0 = (int*)((char*)d_ws + FL_OFF);                          // 512 B
    int* flag1 = flag0 + 128;                                           // 512 B

    hipMemsetAsync((char*)d_ws + FL_OFF, 0, 1024, stream);
    // zero parity-1 halves: h0(-1) = h1(-1) = 0
    hipMemsetAsync((char*)h0buf + (size_t)BATCH * UNITS * 2, 0,
                   (size_t)BATCH * UNITS * 2, stream);
    hipMemsetAsync((char*)h1buf + (size_t)BATCH * UNITS * 2, 0,
                   (size_t)BATCH * UNITS * 2, stream);
    pack_weights<<<512, 256, 0, stream>>>(W0x, W0h, W1x, W1h, wpack);
    rnn_lsr<<<256, THREADS, 0, stream>>>(
        inputs, emb, b0, b1, wpack, h0buf, h1buf, flag0, flag1,
        Wout, bout, out);
}

// Round 9
// 1024.579 us; speedup vs baseline: 1.9174x; 1.9174x over previous
//
#include <hip/hip_runtime.h>
#include <hip/hip_bf16.h>
#include <math.h>

#define BATCH   1024
#define SEQ     80
#define EMB     512
#define UNITS   512
#define NBG     64           // batch groups (16 rows each)
#define NCG     4            // col groups (128 cols each)
#define ROWS    16
#define COLS    128
#define THREADS 512          // 8 waves; wave w: kc = w&3 (K-chunk), ch = w>>2 (col half)
#define LDW     1544         // LDS row stride (ushort): 1536 + 8 pad

#define H0_OFF   (2u * 1024 * 1024)
#define H1_OFF   (4u * 1024 * 1024)
#define FLAG_OFF (6u * 1024 * 1024)

typedef __attribute__((ext_vector_type(8))) short              bf16x8;
typedef __attribute__((ext_vector_type(8))) unsigned short     u16x8;
typedef __attribute__((ext_vector_type(4))) float              f32x4;
typedef __attribute__((ext_vector_type(2))) unsigned long long u64x2;

__device__ inline unsigned short f2bf(float f) {
    __hip_bfloat16 h = __float2bfloat16(f);
    return *reinterpret_cast<unsigned short*>(&h);
}
__device__ inline float bf2f(unsigned short u) {
    unsigned int x = ((unsigned int)u) << 16;
    return __uint_as_float(x);
}
__device__ inline float tanh_fast(float x) {
    float e = __expf(2.f * x);
    return 1.f - 2.f / (e + 1.f);
}
__device__ inline u16x8 pack8(float4 p0, float4 p1) {
    u16x8 v;
    v[0]=f2bf(p0.x); v[1]=f2bf(p0.y); v[2]=f2bf(p0.z); v[3]=f2bf(p0.w);
    v[4]=f2bf(p1.x); v[5]=f2bf(p1.y); v[6]=f2bf(p1.z); v[7]=f2bf(p1.w);
    return v;
}
__device__ inline unsigned long long ld_u64(const unsigned long long* p) {
    return __hip_atomic_load(p, __ATOMIC_RELAXED, __HIP_MEMORY_SCOPE_AGENT);
}

// ---------------------------------------------------------------------------
// Pack weights into per-(phase, cg, wave, slab) B-fragments, bf16.
// g = ((p*4 + cg)*8 + w)*32 + s ; w = (kc,ch): kc=w&3, ch=w>>2 ; s = ks*4+nt
// elem(lane,j) = Wp[kc*256 + ks*32 + (lane>>4)*8 + j]
//                  [cg*128 + ch*64 + nt*16 + (lane&15)]
// Wp rows: [Wx ; Wh] stacked (K=1024). p0: W0x/W0h ; p1: W1x/W1h.
// ---------------------------------------------------------------------------
__global__ __launch_bounds__(256) void pack_weights(
    const float* __restrict__ W0x, const float* __restrict__ W0h,
    const float* __restrict__ W1x, const float* __restrict__ W1h,
    unsigned short* __restrict__ wpack)
{
    int g    = blockIdx.x * 4 + (threadIdx.x >> 6);   // 0..2047
    int lane = threadIdx.x & 63;
    int p    = g >> 10;
    int cg   = (g >> 8) & 3;
    int w    = (g >> 5) & 7;
    int s    = g & 31;
    int kc   = w & 3;
    int ch   = w >> 2;
    int ks   = s >> 2;
    int nt   = s & 3;
    int col  = cg * COLS + ch * 64 + nt * 16 + (lane & 15);
    int kb   = kc * 256 + ks * 32 + (lane >> 4) * 8;
    const float* Wx = p ? W1x : W0x;
    const float* Wh = p ? W1h : W0h;

    u16x8 v;
#pragma unroll
    for (int j = 0; j < 8; ++j) {
        int k = kb + j;
        float f = (k < 512) ? Wx[(size_t)k * UNITS + col]
                            : Wh[(size_t)(k - 512) * UNITS + col];
        v[j] = f2bf(f);
    }
    *(u16x8*)(wpack + (size_t)g * 512 + lane * 8) = v;
}

// K-split GEMM: wave covers K-chunk kc (256) x 4 n-tiles; chain depth 8,
// 4 independent accumulators, depth-8 B prefetch from L2.
#define RUN_SPLIT(KBASE, WB, AC)                                               \
    do {                                                                       \
        const unsigned short* a_ = hcat + abase + (KBASE);                     \
        bf16x8 Bf_[8];                                                         \
        _Pragma("unroll")                                                      \
        for (int i_ = 0; i_ < 8; ++i_)                                         \
            Bf_[i_] = *(const bf16x8*)((WB) + (size_t)i_ * 512);               \
        _Pragma("unroll")                                                      \
        for (int ks_ = 0; ks_ < 8; ++ks_) {                                    \
            bf16x8 av_ = *(const bf16x8*)(a_ + ks_ * 32);                      \
            _Pragma("unroll")                                                  \
            for (int nt_ = 0; nt_ < 4; ++nt_) {                                \
                int s_ = ks_ * 4 + nt_;                                        \
                bf16x8 b_ = Bf_[s_ & 7];                                       \
                if (s_ + 8 < 32)                                               \
                    Bf_[s_ & 7] = *(const bf16x8*)((WB) + (size_t)(s_+8)*512); \
                AC[nt_] = __builtin_amdgcn_mfma_f32_16x16x32_bf16(             \
                    av_, b_, AC[nt_], 0, 0, 0);                                \
            }                                                                  \
        }                                                                      \
    } while (0)

// write K-partials -> LDS, barrier, 4-way reduce + bias + tanh + publish.
// wave (kc,ch) publishes rows [kc*4,kc*4+4) x cols [ch*64,ch*64+64).
#define RED_PUB(AC, HB, PAR, BIAS)                                             \
    do {                                                                       \
        _Pragma("unroll")                                                      \
        for (int nt_ = 0; nt_ < 4; ++nt_)                                      \
            _Pragma("unroll")                                                  \
            for (int i_ = 0; i_ < 4; ++i_)                                     \
                redbuf[kc * 2048 + (quad * 4 + i_) * 128 + chbase + nt_ * 16   \
                       + l15] = AC[nt_][i_];                                   \
        __syncthreads();                                                       \
        unsigned short* d_ = (HB) + ((size_t)(PAR) * BATCH + rbase + kc * 4)   \
                                    * UNITS + cg * COLS + chbase + lane;       \
        _Pragma("unroll")                                                      \
        for (int i_ = 0; i_ < 4; ++i_) {                                       \
            int ro_ = (kc * 4 + i_) * 128 + chbase + lane;                     \
            float s_ = redbuf[ro_] + redbuf[2048 + ro_] + redbuf[4096 + ro_]   \
                     + redbuf[6144 + ro_] + (BIAS);                            \
            __hip_atomic_store(d_ + (size_t)i_ * UNITS, f2bf(tanh_fast(s_)),   \
                               __ATOMIC_RELAXED, __HIP_MEMORY_SCOPE_AGENT);    \
        }                                                                      \
    } while (0)

// gather full 16x512 h-tile (parity PAR) -> hcat cols [CBASE, CBASE+512)
#define GATHER16(HB, PAR, CBASE)                                               \
    do {                                                                       \
        const unsigned long long* src_ = (const unsigned long long*)           \
            ((HB) + ((size_t)(PAR) * BATCH + rbase) * UNITS);                  \
        int ua_ = gr * 128 + (tid & 63) * 2;                                   \
        int ub_ = ua_ + 8 * 128;                                               \
        unsigned long long q0_ = ld_u64(src_ + ua_);                           \
        unsigned long long q1_ = ld_u64(src_ + ua_ + 1);                       \
        unsigned long long q2_ = ld_u64(src_ + ub_);                           \
        unsigned long long q3_ = ld_u64(src_ + ub_ + 1);                       \
        u64x2 lo_; lo_[0] = q0_; lo_[1] = q1_;                                 \
        u64x2 hi_; hi_[0] = q2_; hi_[1] = q3_;                                 \
        *(u64x2*)(hcat + gr * LDW + (CBASE) + gc)       = lo_;                 \
        *(u64x2*)(hcat + (gr + 8) * LDW + (CBASE) + gc) = hi_;                 \
    } while (0)

// stage x(TT) -> hcat cols 0..511 (wave w rows w, w+8; 16B units)
#define STAGE_X(TT)                                                            \
    do {                                                                       \
        int tn_ = (TT) < SEQ ? (TT) : SEQ - 1;                                 \
        int ia_ = inputs[(rbase + gr) * SEQ + tn_];                            \
        int ib_ = inputs[(rbase + gr + 8) * SEQ + tn_];                        \
        const float4* ea_ = (const float4*)(emb + (size_t)ia_ * EMB + gc);     \
        const float4* eb_ = (const float4*)(emb + (size_t)ib_ * EMB + gc);     \
        float4 f0_ = ea_[0], f1_ = ea_[1], f2_ = eb_[0], f3_ = eb_[1];         \
        *(u16x8*)(hcat + gr * LDW + gc)       = pack8(f0_, f1_);               \
        *(u16x8*)(hcat + (gr + 8) * LDW + gc) = pack8(f2_, f3_);               \
    } while (0)

// ---------------------------------------------------------------------------
// 256 blocks = 64 bg x 4 cg, co-resident (1/CU). Block: 16 rows x 128 cols.
// r0 skeleton (protocol/gather/stage/publish/flags verbatim); GEMM now
// K-split across waves: wave (kc,ch) does K-chunk kc*256 over cols ch*64,
// chain depth 8, 4-acc ILP. Stacked-K makes phase-1 uniform: kc0/1 waves
// consume x (staged), kc2/3 consume h0g -- no separate shadow GEMM.
// Partials reduced in LDS (+1 barrier/phase), bias+tanh+publish as r0.
// ---------------------------------------------------------------------------
__global__ __launch_bounds__(THREADS, 1) void rnn_ks(
    const int*   __restrict__ inputs,
    const float* __restrict__ emb,
    const float* __restrict__ b0,
    const float* __restrict__ b1,
    const unsigned short* __restrict__ wpack,
    unsigned short* __restrict__ h0buf,   // [2][1024][512] bf16
    unsigned short* __restrict__ h1buf,   // [2][1024][512] bf16
    int* __restrict__ flag0,              // [64][4]
    int* __restrict__ flag1,              // [64][4]
    const float* __restrict__ Wout,
    const float* __restrict__ bout,
    float*       __restrict__ out)
{
    __shared__ __align__(16) unsigned short hcat[ROWS * LDW];   // ~48 KB
    __shared__ __align__(16) float redbuf[4 * 16 * 128];        //  32 KB

    const int tid   = threadIdx.x;
    const int w     = tid >> 6;
    const int lane  = tid & 63;
    const int quad  = lane >> 4;
    const int l15   = lane & 15;
    const int cg    = blockIdx.x >> 6;    // 0..3
    const int bg    = blockIdx.x & 63;    // 0..63
    const int rbase = bg * ROWS;

    const int kc     = w & 3;             // K-chunk 0..3 (256 each)
    const int ch     = w >> 2;            // col half 0..1 (64 each)
    const int chbase = ch * 64;

    const int gr = w;                     // staging/gather rows w, w+8
    const int gc = (tid & 63) * 8;        // ushort col of this thread's 16B unit

    const float bias0r = b0[cg * COLS + chbase + lane];
    const float bias1r = b1[cg * COLS + chbase + lane];

    const unsigned short* wb1 = wpack +
        (size_t)((cg * 8 + w) * 32) * 512 + lane * 8;            // phase 1
    const unsigned short* wb2 = wb1 + (size_t)1024 * 512;        // phase 2

    const int abase = l15 * LDW + kc * 256 + quad * 8;
    const int fl    = bg * NCG;

    // ---- prologue: zero h regions (h0(-1)=h1(-1)=0), stage x(0) ----
    for (int i = tid; i < ROWS * 1024; i += THREADS) {
        int r = i >> 10, c = i & 1023;
        hcat[r * LDW + 512 + c] = 0;
    }
    STAGE_X(0);
    __syncthreads();

    for (int t = 0; t < SEQ; ++t) {
        const int par = t & 1;
        const int tgt = t + 1;

        // ---- phase 1: pre0 = [x_t | h0(t-1)] @ [W0x;W0h] (K-split) ----
        f32x4 ac[4];
#pragma unroll
        for (int nt = 0; nt < 4; ++nt) ac[nt] = (f32x4){0.f, 0.f, 0.f, 0.f};
        RUN_SPLIT(0, wb1, ac);
        RED_PUB(ac, h0buf, par, bias0r);              // h0(t)  (BarA inside)
        __syncthreads();                                              // B1
        if (tid == 0)
            __hip_atomic_store(&flag0[fl + cg], tgt,
                               __ATOMIC_RELEASE, __HIP_MEMORY_SCOPE_AGENT);
        if (tid < NCG)
            while (__hip_atomic_load(&flag0[fl + tid],
                                     __ATOMIC_RELAXED, __HIP_MEMORY_SCOPE_AGENT) < tgt)
                __builtin_amdgcn_s_sleep(1);
        __asm__ volatile("" ::: "memory");
        __syncthreads();                                              // B2
        GATHER16(h0buf, par, 512);                    // h0(t) full -> LDS
        STAGE_X(t + 1);                               // x(t+1) -> cols 0..511
        __syncthreads();                                              // B3

        // ---- phase 2: pre1 = [h0(t) | h1(t-1)] @ [W1x;W1h] (K-split) ----
        f32x4 ac2[4];
#pragma unroll
        for (int nt = 0; nt < 4; ++nt) ac2[nt] = (f32x4){0.f, 0.f, 0.f, 0.f};
        RUN_SPLIT(512, wb2, ac2);
        RED_PUB(ac2, h1buf, par, bias1r);             // h1(t)  (BarE inside)
        __syncthreads();                                              // B4
        if (tid == 0)
            __hip_atomic_store(&flag1[fl + cg], tgt,
                               __ATOMIC_RELEASE, __HIP_MEMORY_SCOPE_AGENT);
        if (tid < NCG)
            while (__hip_atomic_load(&flag1[fl + tid],
                                     __ATOMIC_RELAXED, __HIP_MEMORY_SCOPE_AGENT) < tgt)
                __builtin_amdgcn_s_sleep(1);
        __asm__ volatile("" ::: "memory");
        __syncthreads();                                              // B5
        GATHER16(h1buf, par, 1024);                   // h1(t) full -> LDS
        // no trailing barrier: next-step B1..B3 order these writes ahead of
        // the next phase-2 reads; phase 1 never touches cols 1024+.
    }
    __syncthreads();

    // ---- epilogue: out = sigmoid(h1 @ Wout + bout); cg 0 blocks only ----
    if (cg == 0) {
#pragma unroll
        for (int rr = 0; rr < 2; ++rr) {
            int r = w * 2 + rr;
            float s = 0.f;
#pragma unroll
            for (int j = 0; j < 8; ++j) {
                int c = lane + 64 * j;
                s += bf2f(hcat[r * LDW + 1024 + c]) * Wout[c];
            }
#pragma unroll
            for (int off = 32; off > 0; off >>= 1) s += __shfl_down(s, off);
            if (lane == 0) {
                float z = s + bout[0];
                out[rbase + r] = 1.f / (1.f + __expf(-z));
            }
        }
    }
}

extern "C" void kernel_launch(void* const* d_in, const int* in_sizes, int n_in,
                              void* d_out, int out_size, void* d_ws, size_t ws_size,
                              hipStream_t stream) {
    const int*   inputs = (const int*)d_in[0];
    const float* emb    = (const float*)d_in[1];
    const float* W0x    = (const float*)d_in[2];
    const float* W0h    = (const float*)d_in[3];
    const float* b0     = (const float*)d_in[4];
    const float* W1x    = (const float*)d_in[5];
    const float* W1h    = (const float*)d_in[6];
    const float* b1     = (const float*)d_in[7];
    const float* Wout   = (const float*)d_in[8];
    const float* bout   = (const float*)d_in[9];
    float*       out    = (float*)d_out;

    unsigned short* wpack = (unsigned short*)d_ws;                      // 2 MB
    unsigned short* h0buf = (unsigned short*)((char*)d_ws + H0_OFF);    // 2 MB
    unsigned short* h1buf = (unsigned short*)((char*)d_ws + H1_OFF);    // 2 MB
    int* flag0 = (int*)((char*)d_ws + FLAG_OFF);                        // 1 KB
    int* flag1 = flag0 + 256;                                           // 1 KB

    hipMemsetAsync((char*)d_ws + FLAG_OFF, 0, 2048, stream);
    pack_weights<<<512, 256, 0, stream>>>(W0x, W0h, W1x, W1h, wpack);
    rnn_ks<<<NBG * NCG, THREADS, 0, stream>>>(
        inputs, emb, b0, b1, wpack, h0buf, h1buf, flag0, flag1,
        Wout, bout, out);
}